// Round 14
// baseline (28.266 us; speedup 1.0000x reference)
//
#include <hip/hip_runtime.h>
#include <math.h>

#define FFT_N   4096
#define THREADS 256
#define RPB     4                    // rows per block (pipelined)
#define RH 0.70710678118654752f
#define C16 0.92387953251128676f     // cos(2*pi/16)
#define S16 0.38268343236508977f     // sin(2*pi/16)
#define NEG2PI_256  (-2.45436926061702597e-2f)   // -2*pi/256
#define NEG2PI_4096 (-1.53398078788564123e-3f)   // -2*pi/4096

// Output-position map of dft16: X[k] lives in v[POS(k)].
#define POS(k) ((((k) & 3) << 2) | ((k) >> 2))

__device__ __forceinline__ float2 cmul(float2 a, float2 b) {
    return make_float2(a.x * b.x - a.y * b.y, a.x * b.y + a.y * b.x);
}

// Barrier without vmcnt drain, full compiler-fence semantics (R10 lesson):
// wait+barrier fused in ONE asm; prefetched loads / deferred stores stay in flight.
__device__ __forceinline__ void bar_lds() {
    asm volatile("s_waitcnt lgkmcnt(0)\n\ts_barrier" ::: "memory");
}

// In-place DFT-4 (W4 = -i): natural in, natural out.
__device__ __forceinline__ void dft4(float2& a, float2& b, float2& c, float2& d) {
    float2 t0 = make_float2(a.x + c.x, a.y + c.y);
    float2 t1 = make_float2(a.x - c.x, a.y - c.y);
    float2 t2 = make_float2(b.x + d.x, b.y + d.y);
    float2 t3 = make_float2(b.y - d.y, d.x - b.x);   // -i * (b - d)
    a = make_float2(t0.x + t2.x, t0.y + t2.y);
    b = make_float2(t1.x + t3.x, t1.y + t3.y);
    c = make_float2(t0.x - t2.x, t0.y - t2.y);
    d = make_float2(t1.x - t3.x, t1.y - t3.y);
}

// Multiply by W16^E = exp(-2*pi*i*E/16); constant-folded forms.
template<int E>
__device__ __forceinline__ float2 mw16(float2 z) {
    if constexpr (E == 0) return z;
    else if constexpr (E == 4) return make_float2(z.y, -z.x);                    // -i
    else if constexpr (E == 2) return make_float2(RH * (z.x + z.y), RH * (z.y - z.x));
    else if constexpr (E == 6) return make_float2(RH * (z.y - z.x), -RH * (z.x + z.y));
    else if constexpr (E == 1) return cmul(z, make_float2(C16, -S16));
    else if constexpr (E == 3) return cmul(z, make_float2(S16, -C16));
    else /* E == 9 */          return cmul(z, make_float2(-C16, S16));
}

// 16-point DFT, natural input order; output X[k] at v[POS(k)].
__device__ __forceinline__ void dft16(float2 (&v)[16]) {
    dft4(v[0], v[4], v[8],  v[12]);
    dft4(v[1], v[5], v[9],  v[13]);
    dft4(v[2], v[6], v[10], v[14]);
    dft4(v[3], v[7], v[11], v[15]);
    v[5]  = mw16<1>(v[5]);   v[9]  = mw16<2>(v[9]);   v[13] = mw16<3>(v[13]);
    v[6]  = mw16<2>(v[6]);   v[10] = mw16<4>(v[10]);  v[14] = mw16<6>(v[14]);
    v[7]  = mw16<3>(v[7]);   v[11] = mw16<6>(v[11]);  v[15] = mw16<9>(v[15]);
    dft4(v[0],  v[1],  v[2],  v[3]);
    dft4(v[4],  v[5],  v[6],  v[7]);
    dft4(v[8],  v[9],  v[10], v[11]);
    dft4(v[12], v[13], v[14], v[15]);
}

// One 4096-point row with float4 global I/O.
// Middle (stage A/RT1/stage B/RT2/stage C) is the verified R5/R11 skeleton.
// RT0: float4-loaded quads -> padded layout aQ(c,n3) = 320*n3 + 5*(c>>2) + (c&3)
//      (write ~4-way banked, read ~2-way; 5120 float2 = 40 KB).
// RT3: bin k at buf[k ^ ((k>>4)&15)] (bijective low-4 XOR; ~4-way both sides).
// ST: store prev row's outputs (vo) as dense float4, split re/im into two packs.
// PF: prefetch next row's 8 float4 into Lr/Li mid-row (consumed at next RT0w).
template<bool ST, bool PF>
__device__ __forceinline__ void process_row(
    float4 (&Lr)[4], float4 (&Li)[4], float2 (&vo)[16],
    float2* __restrict__ bufQ, float2* __restrict__ buf,
    const int t, const int lo, const int hi, const int w, const int l,
    const float2 (&b)[4], const float2 (&c)[4],
    const float2 (&Pw)[4], const float2 (&zz)[4], const int wb2, const int wb3,
    const float4* __restrict__ xr4_n, const float4* __restrict__ xi4_n,
    float4* __restrict__ yr4_p, float4* __restrict__ yi4_p)
{
    // ---- RT0 write: this row's loaded quads (naturals 4t+m + 1024j) ----
    // n3 = w + 4j, c = 4l + m  ->  aQ = 320*(w+4j) + 5*l + m
    #pragma unroll
    for (int j = 0; j < 4; ++j) {
        const int base = 320 * (w + 4 * j) + 5 * l;
        bufQ[base + 0] = make_float2(Lr[j].x, Li[j].x);
        bufQ[base + 1] = make_float2(Lr[j].y, Li[j].y);
        bufQ[base + 2] = make_float2(Lr[j].z, Li[j].z);
        bufQ[base + 3] = make_float2(Lr[j].w, Li[j].w);
    }
    if constexpr (ST) {       // deferred stores, re plane (dense float4)
        #pragma unroll
        for (int d = 0; d < 4; ++d)
            yr4_p[t + (d << 8)] = make_float4(vo[4*d].x, vo[4*d+1].x,
                                              vo[4*d+2].x, vo[4*d+3].x);
    }
    bar_lds();

    // ---- RT0 read: column c = t, all n3 ----
    float2 v[16];
    {
        const int rb = 5 * (t >> 2) + (t & 3);
        #pragma unroll
        for (int n3 = 0; n3 < 16; ++n3)
            v[n3] = bufQ[rb + 320 * n3];
    }

    // ---- Stage A: DFT16 over n3; twiddle W256^{n2*k3}; RT1 write ----
    dft16(v);
    #pragma unroll
    for (int k3 = 0; k3 < 16; ++k3) {
        float2 z = v[POS(k3)];
        if (k3 & 3)  z = cmul(z, b[k3 & 3]);
        if (k3 >> 2) z = cmul(z, c[k3 >> 2]);
        buf[t + (k3 << 8)] = z;
    }
    if constexpr (ST) {       // deferred stores, im plane
        #pragma unroll
        for (int d = 0; d < 4; ++d)
            yi4_p[t + (d << 8)] = make_float4(vo[4*d].y, vo[4*d+1].y,
                                              vo[4*d+2].y, vo[4*d+3].y);
    }
    bar_lds();

    // RT1 read: u[n2] = buf[n1 + 16*n2 + 256*k3]
    #pragma unroll
    for (int n2 = 0; n2 < 16; ++n2)
        v[n2] = buf[lo + (n2 << 4) + (hi << 8)];
    bar_lds();   // buf reused by RT2 writes

    // ---- Prefetch next row (issue only; drains under stages B/C) ----
    if constexpr (PF) {
        #pragma unroll
        for (int j = 0; j < 4; ++j) {
            Lr[j] = xr4_n[t + (j << 8)];
            Li[j] = xi4_n[t + (j << 8)];
        }
    }

    // ---- Stage B: DFT16 over n2; twiddle; RT2 write (R7-verified swizzle) ----
    dft16(v);
    #pragma unroll
    for (int k2 = 0; k2 < 16; ++k2) {
        float2 u = cmul(v[POS(k2)], Pw[k2 & 3]);
        if (k2 >> 2) u = cmul(u, zz[k2 >> 2]);
        buf[wb2 + (k2 << 4)] = u;
    }
    bar_lds();

    // RT2 read: w[n1] = buf[(k3^n1) + 16*k2 + 256*n1]
    #pragma unroll
    for (int m = 0; m < 16; ++m)
        v[m] = buf[(lo ^ m) + (hi << 4) + (m << 8)];

    // ---- Stage C: DFT16 over n1 ----
    dft16(v);
    bar_lds();   // all RT2 reads done -> buf free for RT3 writes

    // ---- RT3 write: bin k = t + 256*k1 at swizzled addr wb3 + 256*k1 ----
    #pragma unroll
    for (int k1 = 0; k1 < 16; ++k1)
        buf[wb3 + (k1 << 8)] = v[POS(k1)];
    bar_lds();

    // ---- RT3 read: bins 4t+m+1024d -> vo[4d+m] (stored next row as float4) ----
    {
        const int x = (t >> 2) & 15;
        #pragma unroll
        for (int d = 0; d < 4; ++d) {
            #pragma unroll
            for (int m = 0; m < 4; ++m) {
                const int k = 4 * t + m + (d << 10);
                vo[4 * d + m] = buf[k ^ x];
            }
        }
    }
    // Next row's first bar_lds orders RT3r (buf) before next RT1w (buf), and
    // next RT0w targets bufQ (disjoint) -> no extra barrier needed here.
}

__global__ __launch_bounds__(THREADS, 2)
void fft4096_v4(const float* __restrict__ xre, const float* __restrict__ xim,
                float* __restrict__ yre, float* __restrict__ yim)
{
    __shared__ float2 bufQ[5120];   // 40 KB, RT0 padded layout
    __shared__ float2 buf[FFT_N];   // 32 KB, RT1/RT2/RT3

    const int t  = threadIdx.x;
    const int lo = t & 15;
    const int hi = t >> 4;
    const int w  = t >> 6;
    const int l  = t & 63;

    // Hoisted row-invariant twiddle constants (depend on t only).
    float2 b[4], c[4], Pw[4], zz[4];
    {
        float sn, cs;
        __sincosf((float)hi * NEG2PI_256, &sn, &cs);
        b[0] = make_float2(1.f, 0.f);
        b[1] = make_float2(cs, sn);
        b[2] = cmul(b[1], b[1]);
        b[3] = cmul(b[2], b[1]);
        c[0] = make_float2(1.f, 0.f);
        c[1] = cmul(b[2], b[2]);        // W256^{4*hi}
        c[2] = cmul(c[1], c[1]);
        c[3] = cmul(c[2], c[1]);
        __sincosf((float)(lo * hi) * NEG2PI_4096, &sn, &cs);
        const float2 P = make_float2(cs, sn);
        __sincosf((float)lo * NEG2PI_256, &sn, &cs);
        float2 w1 = make_float2(cs, sn);          // W4096^{16*n1}
        float2 w2 = cmul(w1, w1);
        float2 w3 = cmul(w2, w1);
        Pw[0] = P;
        Pw[1] = cmul(P, w1);
        Pw[2] = cmul(P, w2);
        Pw[3] = cmul(P, w3);
        zz[0] = make_float2(1.f, 0.f);
        zz[1] = cmul(w2, w2);                     // W256^{4*n1}
        zz[2] = cmul(zz[1], zz[1]);
        zz[3] = cmul(zz[2], zz[1]);
    }
    const int wb2 = (lo ^ hi) + (lo << 8);
    const int wb3 = (lo ^ hi) + (hi << 4);   // a3(t+256k1) = wb3 + 256*k1

    // 4 consecutive rows per block: loads 1 row ahead, stores 1 row behind.
    const size_t r0 = (size_t)blockIdx.x * RPB * FFT_N;
    const float4* xr4 = (const float4*)(xre + r0);
    const float4* xi4 = (const float4*)(xim + r0);
    float4*       yr4 = (float4*)(yre + r0);
    float4*       yi4 = (float4*)(yim + r0);
    const int Q = FFT_N / 4;   // 1024 float4 per row

    float4 Lr[4], Li[4];
    float2 vo[16];
    #pragma unroll
    for (int j = 0; j < 4; ++j) {               // prologue: load row 0 (dense float4)
        Lr[j] = xr4[t + (j << 8)];
        Li[j] = xi4[t + (j << 8)];
    }

    process_row<false, true >(Lr, Li, vo, bufQ, buf, t, lo, hi, w, l,
                              b, c, Pw, zz, wb2, wb3,
                              xr4 + Q,     xi4 + Q,     yr4,         yi4);
    process_row<true , true >(Lr, Li, vo, bufQ, buf, t, lo, hi, w, l,
                              b, c, Pw, zz, wb2, wb3,
                              xr4 + 2 * Q, xi4 + 2 * Q, yr4,         yi4);
    process_row<true , true >(Lr, Li, vo, bufQ, buf, t, lo, hi, w, l,
                              b, c, Pw, zz, wb2, wb3,
                              xr4 + 3 * Q, xi4 + 3 * Q, yr4 + Q,     yi4 + Q);
    process_row<true , false>(Lr, Li, vo, bufQ, buf, t, lo, hi, w, l,
                              b, c, Pw, zz, wb2, wb3,
                              xr4,         xi4,         yr4 + 2 * Q, yi4 + 2 * Q);

    // Epilogue: flush row 3's outputs (dense float4).
    #pragma unroll
    for (int d = 0; d < 4; ++d) {
        yr4[3 * Q + t + (d << 8)] = make_float4(vo[4*d].x, vo[4*d+1].x,
                                                vo[4*d+2].x, vo[4*d+3].x);
        yi4[3 * Q + t + (d << 8)] = make_float4(vo[4*d].y, vo[4*d+1].y,
                                                vo[4*d+2].y, vo[4*d+3].y);
    }
}

extern "C" void kernel_launch(void* const* d_in, const int* in_sizes, int n_in,
                              void* d_out, int out_size, void* d_ws, size_t ws_size,
                              hipStream_t stream) {
    const float* xre = (const float*)d_in[0];
    const float* xim = (const float*)d_in[1];
    const int total = in_sizes[0];          // B * N
    const int rows  = total / FFT_N;        // 2048
    float* yre = (float*)d_out;
    float* yim = yre + total;
    fft4096_v4<<<dim3(rows / RPB), dim3(THREADS), 0, stream>>>(xre, xim, yre, yim);
}

// Round 15
// 26.233 us; speedup vs baseline: 1.0775x; 1.0775x over previous
//
#include <hip/hip_runtime.h>
#include <math.h>

#define FFT_N   4096
#define THREADS 256
#define RPB     4                    // rows per block (pipelined)
#define RH 0.70710678118654752f
#define C16 0.92387953251128676f     // cos(2*pi/16)
#define S16 0.38268343236508977f     // sin(2*pi/16)
#define NEG2PI_256  (-2.45436926061702597e-2f)   // -2*pi/256
#define NEG2PI_4096 (-1.53398078788564123e-3f)   // -2*pi/4096

// Output-position map of dft16: X[k] lives in v[POS(k)].
#define POS(k) ((((k) & 3) << 2) | ((k) >> 2))

__device__ __forceinline__ float2 cmul(float2 a, float2 b) {
    return make_float2(a.x * b.x - a.y * b.y, a.x * b.y + a.y * b.x);
}

// Barrier without vmcnt drain, with full compiler-fence semantics (R10 lesson):
// wait+barrier fused in ONE asm. Prefetch loads / deferred stores stay in flight.
__device__ __forceinline__ void bar_lds() {
    asm volatile("s_waitcnt lgkmcnt(0)\n\ts_barrier" ::: "memory");
}

// In-place DFT-4 (W4 = -i): natural in, natural out.
__device__ __forceinline__ void dft4(float2& a, float2& b, float2& c, float2& d) {
    float2 t0 = make_float2(a.x + c.x, a.y + c.y);
    float2 t1 = make_float2(a.x - c.x, a.y - c.y);
    float2 t2 = make_float2(b.x + d.x, b.y + d.y);
    float2 t3 = make_float2(b.y - d.y, d.x - b.x);   // -i * (b - d)
    a = make_float2(t0.x + t2.x, t0.y + t2.y);
    b = make_float2(t1.x + t3.x, t1.y + t3.y);
    c = make_float2(t0.x - t2.x, t0.y - t2.y);
    d = make_float2(t1.x - t3.x, t1.y - t3.y);
}

// Multiply by W16^E = exp(-2*pi*i*E/16); constant-folded forms.
template<int E>
__device__ __forceinline__ float2 mw16(float2 z) {
    if constexpr (E == 0) return z;
    else if constexpr (E == 4) return make_float2(z.y, -z.x);                    // -i
    else if constexpr (E == 2) return make_float2(RH * (z.x + z.y), RH * (z.y - z.x));
    else if constexpr (E == 6) return make_float2(RH * (z.y - z.x), -RH * (z.x + z.y));
    else if constexpr (E == 1) return cmul(z, make_float2(C16, -S16));
    else if constexpr (E == 3) return cmul(z, make_float2(S16, -C16));
    else /* E == 9 */          return cmul(z, make_float2(-C16, S16));
}

// 16-point DFT, natural input order; output X[k] at v[POS(k)].
__device__ __forceinline__ void dft16(float2 (&v)[16]) {
    dft4(v[0], v[4], v[8],  v[12]);
    dft4(v[1], v[5], v[9],  v[13]);
    dft4(v[2], v[6], v[10], v[14]);
    dft4(v[3], v[7], v[11], v[15]);
    v[5]  = mw16<1>(v[5]);   v[9]  = mw16<2>(v[9]);   v[13] = mw16<3>(v[13]);
    v[6]  = mw16<2>(v[6]);   v[10] = mw16<4>(v[10]);  v[14] = mw16<6>(v[14]);
    v[7]  = mw16<3>(v[7]);   v[11] = mw16<6>(v[11]);  v[15] = mw16<9>(v[15]);
    dft4(v[0],  v[1],  v[2],  v[3]);
    dft4(v[4],  v[5],  v[6],  v[7]);
    dft4(v[8],  v[9],  v[10], v[11]);
    dft4(v[12], v[13], v[14], v[15]);
}

// One full 4096-point row (verified R5/R13 skeleton) with DUAL LDS buffers:
// RT1 uses bufA, RT2 uses bufB -> only 2 barriers per row.
// Hazard audit (4 waves, per-wave program order):
//   bar1: RT1w(A) -> RT1r(A).   bar2: RT2w(B) -> RT2r(B).
//   cross-row WAR A: RT1r(i) < bar2(i) < RT1w(i+1)  (all waves)  OK
//   cross-row WAR B: RT2r(i) < bar1(i+1) < RT2w(i+1)             OK
// Fine-grained VMEM streaming (R13): next row's loads (PF) and previous row's
// stores (ST) split into quad-packs interleaved into every phase gap.
// 4096 = 16*16*16 DIT: n = n1 + 16*n2 + 256*n3, k = k3 + 16*k2 + 256*k1.
template<bool PF, bool ST>
__device__ __forceinline__ void process_row(
    float2 (&v)[16], float2 (&vn)[16], float2 (&vo)[16],
    float2* __restrict__ bufA, float2* __restrict__ bufB,
    const int t, const int lo, const int hi,
    const float2 (&b)[4], const float2 (&c)[4],
    const float2 (&Pw)[4], const float2 (&zz)[4], const int wb2,
    const float* __restrict__ xr_n, const float* __restrict__ xi_n,
    float* __restrict__ yr_p, float* __restrict__ yi_p)
{
    // Quad-pack helpers (8 VMEM instrs each).
#define LPACK(q)                                                         \
    if constexpr (PF) {                                                  \
        _Pragma("unroll")                                                \
        for (int n3 = 4*(q); n3 < 4*(q)+4; ++n3) {                       \
            vn[n3].x = xr_n[t + (n3 << 8)];                              \
            vn[n3].y = xi_n[t + (n3 << 8)];                              \
        }                                                                \
    }
#define SPACK(q)                                                         \
    if constexpr (ST) {                                                  \
        _Pragma("unroll")                                                \
        for (int k1 = 4*(q); k1 < 4*(q)+4; ++k1) {                       \
            __builtin_nontemporal_store(vo[k1].x, &yr_p[t + (k1 << 8)]); \
            __builtin_nontemporal_store(vo[k1].y, &yi_p[t + (k1 << 8)]); \
        }                                                                \
    }

    LPACK(0)

    // ---- Stage A: DFT16 over n3 (thread t = n1 + 16*n2) ----
    dft16(v);
    SPACK(0)

    // Twiddle W256^{n2*k3} = b[k3&3]*c[k3>>2]; write RT1: bufA[t + 256*k3]
    #pragma unroll
    for (int k3 = 0; k3 < 16; ++k3) {
        float2 z = v[POS(k3)];
        if (k3 & 3)  z = cmul(z, b[k3 & 3]);
        if (k3 >> 2) z = cmul(z, c[k3 >> 2]);
        bufA[t + (k3 << 8)] = z;
    }
    LPACK(1)
    bar_lds();   // bar1: RT1w -> RT1r

    // RT1 read: u[n2] = bufA[n1 + 16*n2 + 256*k3]
    #pragma unroll
    for (int n2 = 0; n2 < 16; ++n2)
        v[n2] = bufA[lo + (n2 << 4) + (hi << 8)];
    SPACK(1)

    // ---- Stage B: DFT16 over n2 ----   (no barrier: RT2 targets bufB)
    dft16(v);
    LPACK(2)
    SPACK(2)

    // Twiddle W4096^{n1*(k3+16*k2)} = Pw[k2&3]*zz[k2>>2]; write RT2 swizzled:
    // bufB[(k3^n1) + 16*k2 + 256*n1]   (wb2 = (hi^lo) + 256*lo, R7-verified)
    #pragma unroll
    for (int k2 = 0; k2 < 16; ++k2) {
        float2 u = cmul(v[POS(k2)], Pw[k2 & 3]);
        if (k2 >> 2) u = cmul(u, zz[k2 >> 2]);
        bufB[wb2 + (k2 << 4)] = u;
    }
    SPACK(3)    // last store pack BEFORE vo is overwritten below
    bar_lds();   // bar2: RT2w -> RT2r

    // RT2 read: w[n1] = bufB[(k3^n1) + 16*k2 + 256*n1]
    #pragma unroll
    for (int m = 0; m < 16; ++m)
        v[m] = bufB[(lo ^ m) + (hi << 4) + (m << 8)];
    LPACK(3)

    // ---- Stage C: DFT16 over n1; outputs DEFERRED into vo (stored next row) ----
    dft16(v);
    #pragma unroll
    for (int k1 = 0; k1 < 16; ++k1)
        vo[k1] = v[POS(k1)];
    // No end-of-row barrier needed (see hazard audit above).

#undef LPACK
#undef SPACK
}

__global__ __launch_bounds__(THREADS)
void fft4096_dbuf(const float* __restrict__ xre, const float* __restrict__ xim,
                  float* __restrict__ yre, float* __restrict__ yim)
{
    __shared__ float2 bufA[FFT_N];   // 32 KB, RT1
    __shared__ float2 bufB[FFT_N];   // 32 KB, RT2  (64 KB total -> 2 blocks/CU)

    const int t  = threadIdx.x;
    const int lo = t & 15;
    const int hi = t >> 4;

    // Hoisted row-invariant twiddle constants.
    float2 b[4], c[4], Pw[4], zz[4];
    {
        float sn, cs;
        __sincosf((float)hi * NEG2PI_256, &sn, &cs);
        b[0] = make_float2(1.f, 0.f);
        b[1] = make_float2(cs, sn);
        b[2] = cmul(b[1], b[1]);
        b[3] = cmul(b[2], b[1]);
        c[0] = make_float2(1.f, 0.f);
        c[1] = cmul(b[2], b[2]);        // W256^{4*hi}
        c[2] = cmul(c[1], c[1]);
        c[3] = cmul(c[2], c[1]);
        __sincosf((float)(lo * hi) * NEG2PI_4096, &sn, &cs);
        const float2 P = make_float2(cs, sn);
        __sincosf((float)lo * NEG2PI_256, &sn, &cs);
        float2 w1 = make_float2(cs, sn);          // W4096^{16*n1}
        float2 w2 = cmul(w1, w1);
        float2 w3 = cmul(w2, w1);
        Pw[0] = P;
        Pw[1] = cmul(P, w1);
        Pw[2] = cmul(P, w2);
        Pw[3] = cmul(P, w3);
        zz[0] = make_float2(1.f, 0.f);
        zz[1] = cmul(w2, w2);                     // W256^{4*n1}
        zz[2] = cmul(zz[1], zz[1]);
        zz[3] = cmul(zz[2], zz[1]);
    }
    const int wb2 = (lo ^ hi) + (lo << 8);

    // 4 consecutive rows per block: loads 1 row ahead, stores 1 row behind.
    const size_t r0 = (size_t)blockIdx.x * RPB * FFT_N;
    const float* xr = xre + r0;
    const float* xi = xim + r0;
    float*       yr = yre + r0;
    float*       yi = yim + r0;

    float2 va[16], vb[16], vo[16];
    #pragma unroll
    for (int n3 = 0; n3 < 16; ++n3) {            // load row 0 (prologue burst)
        va[n3].x = xr[t + (n3 << 8)];
        va[n3].y = xi[t + (n3 << 8)];
    }

    // row 0: no deferred stores yet
    process_row<true , false>(va, vb, vo, bufA, bufB, t, lo, hi, b, c, Pw, zz, wb2,
                              xr + FFT_N,     xi + FFT_N,     yr, yi);
    // row 1: stores row 0
    process_row<true , true >(vb, va, vo, bufA, bufB, t, lo, hi, b, c, Pw, zz, wb2,
                              xr + 2 * FFT_N, xi + 2 * FFT_N, yr,             yi);
    // row 2: stores row 1
    process_row<true , true >(va, vb, vo, bufA, bufB, t, lo, hi, b, c, Pw, zz, wb2,
                              xr + 3 * FFT_N, xi + 3 * FFT_N, yr + FFT_N,     yi + FFT_N);
    // row 3: stores row 2, no prefetch
    process_row<false, true >(vb, va, vo, bufA, bufB, t, lo, hi, b, c, Pw, zz, wb2,
                              xr,             xi,             yr + 2 * FFT_N, yi + 2 * FFT_N);

    // Epilogue: flush row 3's outputs.
    #pragma unroll
    for (int k1 = 0; k1 < 16; ++k1) {
        __builtin_nontemporal_store(vo[k1].x, &yr[3 * FFT_N + t + (k1 << 8)]);
        __builtin_nontemporal_store(vo[k1].y, &yi[3 * FFT_N + t + (k1 << 8)]);
    }
}

extern "C" void kernel_launch(void* const* d_in, const int* in_sizes, int n_in,
                              void* d_out, int out_size, void* d_ws, size_t ws_size,
                              hipStream_t stream) {
    const float* xre = (const float*)d_in[0];
    const float* xim = (const float*)d_in[1];
    const int total = in_sizes[0];          // B * N
    const int rows  = total / FFT_N;        // 2048
    float* yre = (float*)d_out;
    float* yim = yre + total;
    fft4096_dbuf<<<dim3(rows / RPB), dim3(THREADS), 0, stream>>>(xre, xim, yre, yim);
}